// Round 7
// baseline (282.426 us; speedup 1.0000x reference)
//
#include <hip/hip_runtime.h>

// Problem constants: B=4, N_TOK=16384, DIM=256, NH=8, NP=4, HD=32, H=W=128.
// M = 65536 rows.  Weights are tiny (s=0.02) => bf16 GEMM error << 2% threshold.

typedef __attribute__((ext_vector_type(8))) short bf16x8;
typedef __attribute__((ext_vector_type(4))) float f32x4;

__device__ __forceinline__ short f2bf(float f) {
  unsigned u = __float_as_uint(f);
  u = u + 0x7FFFu + ((u >> 16) & 1u);   // round-to-nearest-even
  return (short)(u >> 16);
}
__device__ __forceinline__ float bf2f(short s) {
  return __uint_as_float(((unsigned)(unsigned short)s) << 16);
}

__device__ __forceinline__ void gload16(const void* g, void* l) {
  __builtin_amdgcn_global_load_lds(
      (const __attribute__((address_space(1))) unsigned int*)g,
      (__attribute__((address_space(3))) unsigned int*)l, 16, 0, 0);
}

// ---------------------------------------------------------------- k_prep
// wcat[384][256] bf16 = concat(v_w[256], aw_w[32], off_w[64], zeros[32])
// wproj[256][256] bf16 = proj_w
__global__ __launch_bounds__(256) void k_prep(
    const float* __restrict__ v_w, const float* __restrict__ aw_w,
    const float* __restrict__ off_w, const float* __restrict__ proj_w,
    short* __restrict__ wcat, short* __restrict__ wproj)
{
  int idx = blockIdx.x * 256 + threadIdx.x;   // grid 640 -> idx < 163840
  if (idx < 384 * 256) {
    int row = idx >> 8;
    float val = 0.f;
    if (row < 256)      val = v_w[idx];
    else if (row < 288) val = aw_w[idx - 256 * 256];
    else if (row < 352) val = off_w[idx - 288 * 256];
    wcat[idx] = f2bf(val);
  } else {
    int j = idx - 384 * 256;                  // < 65536
    wproj[j] = f2bf(proj_w[j]);
  }
}

// ---------------------------------------------------------------- k_proj
// Single-pass: block = 64 rows x ALL 384 cols.  4 waves, wave = 64x96
// (4x6 frags of 16x16x32), BK=64, 4 k-tiles.  B via global_load_lds with
// pre-swizzled source; A reg-staged f32->bf16 with swizzled ds_write.
// Epilogue: v -> bf16 vbuf; aw -> fused softmax (shfl) -> weights f32;
// off -> f32.
__global__ __launch_bounds__(256) void k_proj(
    const float* __restrict__ x, const short* __restrict__ wcat,
    const float* __restrict__ v_b, const float* __restrict__ aw_b,
    const float* __restrict__ off_b,
    unsigned short* __restrict__ vbuf,   // [32][16384][32] bf16 (= d_out scratch)
    float* __restrict__ wts,             // [32][16384][4]  (softmaxed)
    float* __restrict__ offraw)          // [32][16384][4][2]
{
  __shared__ short As[64 * 64];
  __shared__ short Bs[384 * 64];
  const int tid  = threadIdx.x;
  const int wave = tid >> 6, lane = tid & 63;
  const int row0 = blockIdx.x << 6;

  const int ar  = tid >> 2;           // A-stage row 0..63
  const int seg = tid & 3;            // 16-float segment within BK
  const float* xg = x + (size_t)(row0 + ar) * 256 + (seg << 4);

  const int lr = lane & 15, kg = lane >> 4;
  const int cb = wave * 96;           // wave col base

  f32x4 acc[4][6] = {};

  for (int kt = 0; kt < 4; ++kt) {
    // ---- B stage: 12 x global_load_lds per wave (48KB tile)
#pragma unroll
    for (int i = 0; i < 12; ++i) {
      int fb = (wave * 12 + i) << 6;          // flat group base (wave-uniform)
      int f  = fb + lane;
      int r  = f >> 3, s = f & 7;
      int g  = s ^ (r & 7);                   // inverse-swizzled source group
      const short* src = wcat + (size_t)r * 256 + (kt << 6) + (g << 3);
      gload16(src, &Bs[(size_t)fb << 3]);
    }
    // ---- A stage: 4 f32x4 loads -> cvt -> 2 swizzled ds_write_b128
    {
      const float* ap = xg + (kt << 6);
      f32x4 fv[4];
#pragma unroll
      for (int i = 0; i < 4; ++i) fv[i] = ((const f32x4*)ap)[i];
#pragma unroll
      for (int i = 0; i < 2; ++i) {
        bf16x8 v;
#pragma unroll
        for (int j = 0; j < 4; ++j) { v[j] = f2bf(fv[2*i][j]); v[4+j] = f2bf(fv[2*i+1][j]); }
        int g = (seg << 1) + i;               // logical group 0..7
        int s = g ^ (ar & 7);
        *(bf16x8*)&As[(ar << 6) + (s << 3)] = v;
      }
    }
    __syncthreads();   // drains vmcnt (gload_lds) + lgkm (ds_write)

#pragma unroll
    for (int ks = 0; ks < 2; ++ks) {
      bf16x8 a[4], b[6];
#pragma unroll
      for (int m = 0; m < 4; ++m) {
        int r = (m << 4) + lr;
        int g = (ks << 2) + kg;
        a[m] = *(const bf16x8*)&As[(r << 6) + ((g ^ (r & 7)) << 3)];
      }
#pragma unroll
      for (int n = 0; n < 6; ++n) {
        int r = cb + (n << 4) + lr;
        int g = (ks << 2) + kg;
        b[n] = *(const bf16x8*)&Bs[(r << 6) + ((g ^ (r & 7)) << 3)];
      }
#pragma unroll
      for (int m = 0; m < 4; ++m)
#pragma unroll
        for (int n = 0; n < 6; ++n)
          acc[m][n] = __builtin_amdgcn_mfma_f32_16x16x32_bf16(a[m], b[n], acc[m][n], 0, 0, 0);
    }
    __syncthreads();
  }

  // epilogue: C/D layout col=lane&15, row=(lane>>4)*4+reg  [m89-verified]
  // Region per 16-wide frag is wave-uniform (boundaries 256/288/352 are 16-aligned).
#pragma unroll
  for (int n = 0; n < 6; ++n) {
    const int cbase = cb + (n << 4);
    if (cbase >= 352) continue;               // padding cols
#pragma unroll
    for (int m = 0; m < 4; ++m) {
#pragma unroll
      for (int j = 0; j < 4; ++j) {
        int r = row0 + (m << 4) + (kg << 2) + j;
        int b_ = r >> 14, nn = r & 16383;
        float v = acc[m][n][j];
        if (cbase < 256) {
          int c = cbase + lr;
          int h = c >> 5, d = c & 31;
          float val = v + v_b[c];
          vbuf[(((size_t)((b_ << 3) + h) << 14) + nn) * 32 + d] = (unsigned short)f2bf(val);
        } else if (cbase < 288) {
          int q = cbase - 256 + lr;           // 0..31 ; p = q&3 = lr&3
          float val = v + aw_b[q];
          float mx = fmaxf(val, __shfl_xor(val, 1));
          mx = fmaxf(mx, __shfl_xor(mx, 2));
          float e = __expf(val - mx);
          float s = e + __shfl_xor(e, 1);
          s += __shfl_xor(s, 2);
          float w = __fdividef(e, s);
          int h = q >> 2, p = q & 3;
          wts[(((size_t)((b_ << 3) + h) << 14) + nn) * 4 + p] = w;
        } else {
          int q = cbase - 288 + lr;           // 0..63 ; rest = q&7
          int h = q >> 3, rest = q & 7;
          offraw[(((size_t)((b_ << 3) + h) << 14) + nn) * 8 + rest] = v + off_b[q];
        }
      }
    }
  }
}

// ---------------------------------------------------------------- k_sample
// 4 lanes per (g,n) item; 16B ushort8 bf16 gathers; weights precomputed.
__global__ __launch_bounds__(256) void k_sample(
    const unsigned short* __restrict__ vbuf, const float* __restrict__ wts,
    const float* __restrict__ offraw, unsigned short* __restrict__ attn)
{
  const int tid  = threadIdx.x;
  const int item = (blockIdx.x << 6) + (tid >> 2);   // g*16384 + n
  const int q    = tid & 3;                          // d-slot: d = 8q..8q+7
  const int g = item >> 14, n = item & 16383;
  const float px = (float)(n & 127), py = (float)(n >> 7);

  f32x4 w4 = *(const f32x4*)(wts + (size_t)item * 4);
  const f32x4* opv = (const f32x4*)(offraw + (size_t)item * 8);
  f32x4 o0 = opv[0], o1 = opv[1];
  float wv[4]  = {w4[0], w4[1], w4[2], w4[3]};
  float oxs[4] = {o0[0], o0[2], o1[0], o1[2]};
  float oys[4] = {o0[1], o0[3], o1[1], o1[3]};

  const unsigned short* vg = vbuf + (((size_t)g) << 19) + (q << 3);  // g*16384*32
  float o[8] = {};
#pragma unroll
  for (int p = 0; p < 4; ++p) {
    float gx = px + oxs[p], gy = py + oys[p];
    float x0f = floorf(gx), y0f = floorf(gy);
    float wx1 = gx - x0f, wx0 = 1.f - wx1;
    float wy1 = gy - y0f, wy0 = 1.f - wy1;
    int x0 = (int)x0f, y0 = (int)y0f;
    bool xv0 = (unsigned)x0 < 128u, xv1 = (unsigned)(x0 + 1) < 128u;
    bool yv0 = (unsigned)y0 < 128u, yv1 = (unsigned)(y0 + 1) < 128u;
    const unsigned short* base = vg + (((y0 << 7) + x0) << 5);
    bf16x8 c00 = {}, c10 = {}, c01 = {}, c11 = {};
    if (xv0 & yv0) c00 = *(const bf16x8*)(base);
    if (xv1 & yv0) c10 = *(const bf16x8*)(base + 32);
    if (xv0 & yv1) c01 = *(const bf16x8*)(base + 4096);
    if (xv1 & yv1) c11 = *(const bf16x8*)(base + 4128);
    float w00 = wv[p] * (wy0 * wx0), w10 = wv[p] * (wy0 * wx1);
    float w01 = wv[p] * (wy1 * wx0), w11 = wv[p] * (wy1 * wx1);
#pragma unroll
    for (int j = 0; j < 8; ++j)
      o[j] += w00 * bf2f(c00[j]) + w10 * bf2f(c10[j])
            + w01 * bf2f(c01[j]) + w11 * bf2f(c11[j]);
  }
  int b_ = g >> 3, h = g & 7;
  bf16x8 pk;
#pragma unroll
  for (int j = 0; j < 8; ++j) pk[j] = f2bf(o[j]);
  *(bf16x8*)(attn + ((((size_t)b_ << 14) + n) << 8) + (h << 5) + (q << 3)) = pk;
}

// ---------------------------------------------------------------- k_out
// out[65536][256] = attn @ proj_w.T + proj_b   (f32 output)
// Single-pass: block = 128 rows x 256 cols, 8 waves (2x4), BK=64.
__global__ __launch_bounds__(512) void k_out(
    const unsigned short* __restrict__ attn, const short* __restrict__ wproj,
    const float* __restrict__ proj_b, float* __restrict__ out)
{
  __shared__ short As[128 * 64];
  __shared__ short Bs[256 * 64];
  const int tid  = threadIdx.x;
  const int wave = tid >> 6, lane = tid & 63;
  const int row0 = blockIdx.x << 7;

  const int wr = wave >> 2, wc = wave & 3;
  const int lr = lane & 15, kg = lane >> 4;

  f32x4 acc[4][4] = {};

  for (int kt = 0; kt < 4; ++kt) {
#pragma unroll
    for (int i = 0; i < 2; ++i) {             // A: 128x64 bf16 = 1024 groups
      int fb = ((wave << 1) + i) << 6;
      int f  = fb + lane;
      int r  = f >> 3, s = f & 7;
      int g  = s ^ (r & 7);
      const short* srcA = (const short*)attn + (size_t)(row0 + r) * 256 + (kt << 6) + (g << 3);
      gload16(srcA, &As[(size_t)fb << 3]);
    }
#pragma unroll
    for (int i = 0; i < 4; ++i) {             // B: 256x64 bf16 = 2048 groups
      int fb = ((wave << 2) + i) << 6;
      int f  = fb + lane;
      int r  = f >> 3, s = f & 7;
      int g  = s ^ (r & 7);
      const short* srcB = wproj + (size_t)r * 256 + (kt << 6) + (g << 3);
      gload16(srcB, &Bs[(size_t)fb << 3]);
    }
    __syncthreads();

#pragma unroll
    for (int ks = 0; ks < 2; ++ks) {
      bf16x8 a[4], b[4];
#pragma unroll
      for (int m = 0; m < 4; ++m) {
        int r = (wr << 6) + (m << 4) + lr;
        int g = (ks << 2) + kg;
        a[m] = *(const bf16x8*)&As[(r << 6) + ((g ^ (r & 7)) << 3)];
      }
#pragma unroll
      for (int n = 0; n < 4; ++n) {
        int r = (wc << 6) + (n << 4) + lr;
        int g = (ks << 2) + kg;
        b[n] = *(const bf16x8*)&Bs[(r << 6) + ((g ^ (r & 7)) << 3)];
      }
#pragma unroll
      for (int m = 0; m < 4; ++m)
#pragma unroll
        for (int n = 0; n < 4; ++n)
          acc[m][n] = __builtin_amdgcn_mfma_f32_16x16x32_bf16(a[m], b[n], acc[m][n], 0, 0, 0);
    }
    __syncthreads();
  }

#pragma unroll
  for (int m = 0; m < 4; ++m) {
#pragma unroll
    for (int n = 0; n < 4; ++n) {
#pragma unroll
      for (int j = 0; j < 4; ++j) {
        int r = row0 + (wr << 6) + (m << 4) + (kg << 2) + j;
        int c = (wc << 6) + (n << 4) + lr;
        out[(size_t)r * 256 + c] = acc[m][n][j] + proj_b[c];
      }
    }
  }
}

// ---------------------------------------------------------------- launch
extern "C" void kernel_launch(void* const* d_in, const int* in_sizes, int n_in,
                              void* d_out, int out_size, void* d_ws, size_t ws_size,
                              hipStream_t stream)
{
  const float* x      = (const float*)d_in[0];
  const float* v_w    = (const float*)d_in[1];
  const float* v_b    = (const float*)d_in[2];
  const float* aw_w   = (const float*)d_in[3];
  const float* aw_b   = (const float*)d_in[4];
  const float* off_w  = (const float*)d_in[5];
  const float* off_b  = (const float*)d_in[6];
  const float* proj_w = (const float*)d_in[7];
  const float* proj_b = (const float*)d_in[8];
  float* out = (float*)d_out;

  char* ws = (char*)d_ws;
  short* wcat   = (short*)(ws + 0);               // 196,608 B
  short* wproj  = (short*)(ws + 262144);          // 131,072 B
  float* wts    = (float*)(ws + 1048576);         // 8,388,608 B (softmaxed)
  float* offraw = (float*)(ws + 9437184);         // 16,777,216 B
  unsigned short* attn = (unsigned short*)(ws + 26214400);  // 33,554,432 B
  unsigned short* vbuf = (unsigned short*)d_out;  // reuse d_out as bf16 v maps (32MB)

  hipLaunchKernelGGL(k_prep,   dim3(640),   dim3(256), 0, stream,
                     v_w, aw_w, off_w, proj_w, wcat, wproj);
  hipLaunchKernelGGL(k_proj,   dim3(1024),  dim3(256), 0, stream,
                     x, wcat, v_b, aw_b, off_b, vbuf, wts, offraw);
  hipLaunchKernelGGL(k_sample, dim3(8192),  dim3(256), 0, stream,
                     vbuf, wts, offraw, attn);
  hipLaunchKernelGGL(k_out,    dim3(512),   dim3(512), 0, stream,
                     attn, wproj, proj_b, out);
}

// Round 9
// 233.217 us; speedup vs baseline: 1.2110x; 1.2110x over previous
//
#include <hip/hip_runtime.h>

// Problem constants: B=4, N_TOK=16384, DIM=256, NH=8, NP=4, HD=32, H=W=128.
// M = 65536 rows.  Weights tiny (s=0.02) => bf16 GEMM error << 2% threshold.
//
// GEMM structure (R7 lesson: K=256 is too short for barrier-pipelined tiles;
// latency-bound at low occupancy): B col-slice in LDS ONCE per block (one
// barrier), then waves independently stream 32-row slabs with A fetched
// global->regs. No barriers in the main loop; 16 waves/CU hide latency.

typedef __attribute__((ext_vector_type(8))) short bf16x8;
typedef __attribute__((ext_vector_type(4))) float f32x4;

__device__ __forceinline__ short f2bf(float f) {
  unsigned u = __float_as_uint(f);
  u = u + 0x7FFFu + ((u >> 16) & 1u);   // round-to-nearest-even
  return (short)(u >> 16);
}
__device__ __forceinline__ float bf2f(short s) {
  return __uint_as_float(((unsigned)(unsigned short)s) << 16);
}

__device__ __forceinline__ void gload16(const void* g, void* l) {
  __builtin_amdgcn_global_load_lds(
      (const __attribute__((address_space(1))) unsigned int*)g,
      (__attribute__((address_space(3))) unsigned int*)l, 16, 0, 0);
}

// ---------------------------------------------------------------- k_prep
__global__ __launch_bounds__(256) void k_prep(
    const float* __restrict__ v_w, const float* __restrict__ aw_w,
    const float* __restrict__ off_w, const float* __restrict__ proj_w,
    short* __restrict__ wcat, short* __restrict__ wproj)
{
  int idx = blockIdx.x * 256 + threadIdx.x;   // grid 640
  if (idx < 384 * 256) {
    int row = idx >> 8;
    float val = 0.f;
    if (row < 256)      val = v_w[idx];
    else if (row < 288) val = aw_w[idx - 256 * 256];
    else if (row < 352) val = off_w[idx - 288 * 256];
    wcat[idx] = f2bf(val);
  } else {
    int j = idx - 384 * 256;
    wproj[j] = f2bf(proj_w[j]);
  }
}

// ---------------------------------------------------------------- k_proj
// grid(128, 4): x = row-block (512 rows), y = cp (96-col slice of wcat).
// Block: 8 waves. B-slice [96][256] bf16 in LDS (48KB, 16B-group swizzled).
// Each wave: 2 slabs of 32 rows x 96 cols; A f32 from global -> cvt -> MFMA.
__global__ __launch_bounds__(512, 4) void k_proj(
    const float* __restrict__ x, const short* __restrict__ wcat,
    const float* __restrict__ v_b, const float* __restrict__ aw_b,
    const float* __restrict__ off_b,
    unsigned short* __restrict__ vbuf,   // [32][16384][32] bf16 (= d_out scratch)
    float* __restrict__ wts,             // [32][16384][4]  (softmaxed)
    float* __restrict__ offraw)          // [32][16384][4][2]
{
  __shared__ short Bs[96 * 256];        // [col][k], 16B groups swizzled
  const int tid  = threadIdx.x;
  const int wave = tid >> 6, lane = tid & 63;
  const int cp   = blockIdx.y;          // 0..3
  const int by   = blockIdx.x;          // 0..127
  const int cpb  = cp * 96;

  // ---- B load: 6 x gload16 per thread; linear dest, inverse-swizzled source
#pragma unroll
  for (int i = 0; i < 6; ++i) {
    int f   = i * 512 + tid;            // dest group index
    int col = f >> 5, s = f & 31;
    int g   = (s & 24) | ((s & 7) ^ (col & 7));
    const short* src = wcat + (size_t)(cpb + col) * 256 + (g << 3);
    gload16(src, &Bs[(i * 512 + (wave << 6)) << 3]);
  }
  __syncthreads();   // only barrier in the kernel

  const int lr = lane & 15, kg = lane >> 4;

#pragma unroll
  for (int sl = 0; sl < 2; ++sl) {
    const int sr0 = (by << 9) + ((wave + (sl << 3)) << 5);
    f32x4 acc[2][6] = {};

#pragma unroll
    for (int ks = 0; ks < 8; ++ks) {
      bf16x8 a[2];
#pragma unroll
      for (int rf = 0; rf < 2; ++rf) {
        const float* ap = x + (size_t)(sr0 + (rf << 4) + lr) * 256 + (ks << 5) + (kg << 3);
        f32x4 f0 = *(const f32x4*)ap;
        f32x4 f1 = *(const f32x4*)(ap + 4);
        bf16x8 v;
#pragma unroll
        for (int j = 0; j < 4; ++j) { v[j] = f2bf(f0[j]); v[4 + j] = f2bf(f1[j]); }
        a[rf] = v;
      }
#pragma unroll
      for (int cf = 0; cf < 6; ++cf) {
        int col = (cf << 4) + lr;
        int g = (ks << 2) + kg;
        int s = (g & 24) | ((g & 7) ^ (col & 7));
        bf16x8 b = *(const bf16x8*)&Bs[(col << 8) + (s << 3)];
        acc[0][cf] = __builtin_amdgcn_mfma_f32_16x16x32_bf16(a[0], b, acc[0][cf], 0, 0, 0);
        acc[1][cf] = __builtin_amdgcn_mfma_f32_16x16x32_bf16(a[1], b, acc[1][cf], 0, 0, 0);
      }
    }

    // epilogue: C/D layout col=lane&15, row=kg*4+j  [m89-verified]
#pragma unroll
    for (int cf = 0; cf < 6; ++cf) {
      const int cbase = cpb + (cf << 4);
      if (cbase >= 352) continue;       // padding cols
#pragma unroll
      for (int rf = 0; rf < 2; ++rf) {
#pragma unroll
        for (int j = 0; j < 4; ++j) {
          int r = sr0 + (rf << 4) + (kg << 2) + j;
          int b_ = r >> 14, nn = r & 16383;
          float v = acc[rf][cf][j];
          if (cbase < 256) {
            int c = cbase + lr;
            int h = c >> 5, d = c & 31;
            float val = v + v_b[c];
            vbuf[(((size_t)((b_ << 3) + h) << 14) + nn) * 32 + d] = (unsigned short)f2bf(val);
          } else if (cbase < 288) {
            int q = cbase - 256 + lr;   // p = q&3 = lr&3 ; softmax over 4 lanes
            float val = v + aw_b[q];
            float mx = fmaxf(val, __shfl_xor(val, 1));
            mx = fmaxf(mx, __shfl_xor(mx, 2));
            float e = __expf(val - mx);
            float ssum = e + __shfl_xor(e, 1);
            ssum += __shfl_xor(ssum, 2);
            float w = __fdividef(e, ssum);
            int h = q >> 2, p = q & 3;
            wts[(((size_t)((b_ << 3) + h) << 14) + nn) * 4 + p] = w;
          } else {
            int q = cbase - 288 + lr;   // rest = q&7
            int h = q >> 3, rest = q & 7;
            offraw[(((size_t)((b_ << 3) + h) << 14) + nn) * 8 + rest] = v + off_b[q];
          }
        }
      }
    }
  }
}

// ---------------------------------------------------------------- k_sample
// 4 lanes per (g,n) item; 16B ushort8 bf16 gathers; weights precomputed.
__global__ __launch_bounds__(256) void k_sample(
    const unsigned short* __restrict__ vbuf, const float* __restrict__ wts,
    const float* __restrict__ offraw, unsigned short* __restrict__ attn)
{
  const int tid  = threadIdx.x;
  const int item = (blockIdx.x << 6) + (tid >> 2);   // g*16384 + n
  const int q    = tid & 3;                          // d = 8q..8q+7
  const int g = item >> 14, n = item & 16383;
  const float px = (float)(n & 127), py = (float)(n >> 7);

  f32x4 w4 = *(const f32x4*)(wts + (size_t)item * 4);
  const f32x4* opv = (const f32x4*)(offraw + (size_t)item * 8);
  f32x4 o0 = opv[0], o1 = opv[1];
  float wv[4]  = {w4[0], w4[1], w4[2], w4[3]};
  float oxs[4] = {o0[0], o0[2], o1[0], o1[2]};
  float oys[4] = {o0[1], o0[3], o1[1], o1[3]};

  const unsigned short* vg = vbuf + (((size_t)g) << 19) + (q << 3);
  float o[8] = {};
#pragma unroll
  for (int p = 0; p < 4; ++p) {
    float gx = px + oxs[p], gy = py + oys[p];
    float x0f = floorf(gx), y0f = floorf(gy);
    float wx1 = gx - x0f, wx0 = 1.f - wx1;
    float wy1 = gy - y0f, wy0 = 1.f - wy1;
    int x0 = (int)x0f, y0 = (int)y0f;
    bool xv0 = (unsigned)x0 < 128u, xv1 = (unsigned)(x0 + 1) < 128u;
    bool yv0 = (unsigned)y0 < 128u, yv1 = (unsigned)(y0 + 1) < 128u;
    const unsigned short* base = vg + (((y0 << 7) + x0) << 5);
    bf16x8 c00 = {}, c10 = {}, c01 = {}, c11 = {};
    if (xv0 & yv0) c00 = *(const bf16x8*)(base);
    if (xv1 & yv0) c10 = *(const bf16x8*)(base + 32);
    if (xv0 & yv1) c01 = *(const bf16x8*)(base + 4096);
    if (xv1 & yv1) c11 = *(const bf16x8*)(base + 4128);
    float w00 = wv[p] * (wy0 * wx0), w10 = wv[p] * (wy0 * wx1);
    float w01 = wv[p] * (wy1 * wx0), w11 = wv[p] * (wy1 * wx1);
#pragma unroll
    for (int j = 0; j < 8; ++j)
      o[j] += w00 * bf2f(c00[j]) + w10 * bf2f(c10[j])
            + w01 * bf2f(c01[j]) + w11 * bf2f(c11[j]);
  }
  int b_ = g >> 3, h = g & 7;
  bf16x8 pk;
#pragma unroll
  for (int j = 0; j < 8; ++j) pk[j] = f2bf(o[j]);
  *(bf16x8*)(attn + ((((size_t)b_ << 14) + n) << 8) + (h << 5) + (q << 3)) = pk;
}

// ---------------------------------------------------------------- k_out
// grid(256, 2): x = row-block (256 rows), y = cp (128-col slice of wproj).
// Block: 8 waves. B-slice [128][256] bf16 in LDS (64KB). Wave: 1 slab of
// 32 rows x 128 cols; A (attn, bf16) direct global->reg.
__global__ __launch_bounds__(512, 4) void k_out(
    const unsigned short* __restrict__ attn, const short* __restrict__ wproj,
    const float* __restrict__ proj_b, float* __restrict__ out)
{
  __shared__ short Bs[128 * 256];
  const int tid  = threadIdx.x;
  const int wave = tid >> 6, lane = tid & 63;
  const int cp   = blockIdx.y;          // 0..1
  const int by   = blockIdx.x;          // 0..255
  const int cpb  = cp << 7;

#pragma unroll
  for (int i = 0; i < 8; ++i) {
    int f   = i * 512 + tid;
    int col = f >> 5, s = f & 31;
    int g   = (s & 24) | ((s & 7) ^ (col & 7));
    const short* src = wproj + (size_t)(cpb + col) * 256 + (g << 3);
    gload16(src, &Bs[(i * 512 + (wave << 6)) << 3]);
  }
  __syncthreads();

  const int lr = lane & 15, kg = lane >> 4;
  const int sr0 = (by << 8) + (wave << 5);

  f32x4 acc[2][8] = {};
#pragma unroll
  for (int ks = 0; ks < 8; ++ks) {
    bf16x8 a[2];
#pragma unroll
    for (int rf = 0; rf < 2; ++rf)
      a[rf] = *(const bf16x8*)((const short*)attn +
               (size_t)(sr0 + (rf << 4) + lr) * 256 + (ks << 5) + (kg << 3));
#pragma unroll
    for (int cf = 0; cf < 8; ++cf) {
      int col = (cf << 4) + lr;
      int g = (ks << 2) + kg;
      int s = (g & 24) | ((g & 7) ^ (col & 7));
      bf16x8 b = *(const bf16x8*)&Bs[(col << 8) + (s << 3)];
      acc[0][cf] = __builtin_amdgcn_mfma_f32_16x16x32_bf16(a[0], b, acc[0][cf], 0, 0, 0);
      acc[1][cf] = __builtin_amdgcn_mfma_f32_16x16x32_bf16(a[1], b, acc[1][cf], 0, 0, 0);
    }
  }

#pragma unroll
  for (int cf = 0; cf < 8; ++cf) {
    int c = cpb + (cf << 4) + lr;
    float pb = proj_b[c];
#pragma unroll
    for (int rf = 0; rf < 2; ++rf) {
#pragma unroll
      for (int j = 0; j < 4; ++j) {
        int r = sr0 + (rf << 4) + (kg << 2) + j;
        out[(size_t)r * 256 + c] = acc[rf][cf][j] + pb;
      }
    }
  }
}

// ---------------------------------------------------------------- launch
extern "C" void kernel_launch(void* const* d_in, const int* in_sizes, int n_in,
                              void* d_out, int out_size, void* d_ws, size_t ws_size,
                              hipStream_t stream)
{
  const float* x      = (const float*)d_in[0];
  const float* v_w    = (const float*)d_in[1];
  const float* v_b    = (const float*)d_in[2];
  const float* aw_w   = (const float*)d_in[3];
  const float* aw_b   = (const float*)d_in[4];
  const float* off_w  = (const float*)d_in[5];
  const float* off_b  = (const float*)d_in[6];
  const float* proj_w = (const float*)d_in[7];
  const float* proj_b = (const float*)d_in[8];
  float* out = (float*)d_out;

  char* ws = (char*)d_ws;
  short* wcat   = (short*)(ws + 0);               // 196,608 B
  short* wproj  = (short*)(ws + 262144);          // 131,072 B
  float* wts    = (float*)(ws + 1048576);         // 8,388,608 B (softmaxed)
  float* offraw = (float*)(ws + 9437184);         // 16,777,216 B
  unsigned short* attn = (unsigned short*)(ws + 26214400);  // 33,554,432 B
  unsigned short* vbuf = (unsigned short*)d_out;  // d_out as bf16 v maps (32MB)

  hipLaunchKernelGGL(k_prep,   dim3(640),      dim3(256), 0, stream,
                     v_w, aw_w, off_w, proj_w, wcat, wproj);
  hipLaunchKernelGGL(k_proj,   dim3(128, 4),   dim3(512), 0, stream,
                     x, wcat, v_b, aw_b, off_b, vbuf, wts, offraw);
  hipLaunchKernelGGL(k_sample, dim3(8192),     dim3(256), 0, stream,
                     vbuf, wts, offraw, attn);
  hipLaunchKernelGGL(k_out,    dim3(256, 2),   dim3(512), 0, stream,
                     attn, wproj, proj_b, out);
}